// Round 13
// baseline (277.591 us; speedup 1.0000x reference)
//
#include <hip/hip_runtime.h>

// SNN forward: [GEMM1+scan1 fused, 128x128, barrier-free K-loop with
// FRAGMENT-ORDER pre-swizzled operands => every fragment load is one
// contiguous 1KB wave read] -> GEMM2 (dbuf) -> scan2 (LDS-staged, static ring).
// f16 split-2: W = hi + lo (both f16), residual ~2^-24 => fp32-grade MFMA.
// Lessons: ring/dbuf arrays need compile-time indices (R9); per-iter
// barrier+DMA drains cost ~2x (R7/R10); scattered per-lane fragment loads
// cost 2x in L2 transactions (R11) — fix = fragment-order layout.
//
// Layouts:
//   Xf [n][c 4][wm 2][kk 8][(i*16+fr)*32 + kq*8+e]  f16, t padded to 512
//   Wf [ht 8][wn 2][kk 8][(j*16+fr)*32 + kq*8+e]    f16 hi+lo
//   s1b [n*t][H] f16 row-major (gemm2 input, unchanged)

#define NN 64
#define II 256
#define HH 1024
#define OO 18
#define TT 500

#define D_SR 0.9048374180359595f   // exp(-1/10)
#define C_SR 0.27182818284590454f  // e/10
#define D_RF 0.36787944117144233f  // exp(-1)
#define C_RF 2.718281828459045f    // e
#define THETA 10.0f
#define REFS (-20.0f)

typedef _Float16 f16;
typedef _Float16 f16x2 __attribute__((ext_vector_type(2)));
typedef _Float16 f16x8 __attribute__((ext_vector_type(8)));
typedef float f32x4 __attribute__((ext_vector_type(4)));

__device__ __forceinline__ void gl2lds16(const void* g, void* l) {
    __builtin_amdgcn_global_load_lds(
        (const __attribute__((address_space(1))) void*)g,
        (__attribute__((address_space(3))) void*)l, 16, 0, 0);
}

// ---------------- prep: X [N][I][T] f32 -> Xf fragment-order f16 ------------
__launch_bounds__(256)
__global__ void prep_x(const float* __restrict__ X, f16* __restrict__ Xf) {
    __shared__ float tile[64][65];
    const int n = blockIdx.z, i0 = blockIdx.y * 64, t0 = blockIdx.x * 64;
    const int tx = threadIdx.x & 63, q = threadIdx.x >> 6;
    const float* Xn = X + (size_t)n * II * TT;
#pragma unroll 4
    for (int j = 0; j < 16; ++j) {
        int il = j * 4 + q;
        int t = t0 + tx;
        tile[il][tx] = (t < TT) ? Xn[(size_t)(i0 + il) * TT + t] : 0.f;
    }
    __syncthreads();
#pragma unroll 4
    for (int j = 0; j < 16; ++j) {
        int tl = j * 4 + q;
        int t = t0 + tl;          // 0..511, zero-padded past TT
        int k = i0 + tx;
        int c = t >> 7, r = t & 127, wm = r >> 6, r2 = r & 63;
        int ii = r2 >> 4, fr = r2 & 15;
        int kk = k >> 5, k2 = k & 31;
        size_t dst = ((((size_t)n * 4 + c) * 2 + wm) * 8 + kk) * 2048
                   + (ii * 16 + fr) * 32 + k2;
        Xf[dst] = (f16)tile[tx][tl];
    }
}

// ---------------- prep: W1 -> fragment-order f16 hi/lo ----------------------
__launch_bounds__(256)
__global__ void prep_w1(const float* __restrict__ W1, f16* __restrict__ Wh,
                        f16* __restrict__ Wl) {
    int idx = blockIdx.x * 256 + threadIdx.x;  // < HH*II
    int h = idx >> 8, k = idx & 255;
    float w = W1[idx];
    f16 hi = (f16)w;
    f16 lo = (f16)(w - (float)hi);
    int ht = h >> 7, hr = h & 127, wn = hr >> 6, hr2 = hr & 63;
    int j = hr2 >> 4, fr = hr2 & 15;
    int kk = k >> 5, k2 = k & 31;
    size_t dst = (((size_t)(ht * 2 + wn) * 8) + kk) * 2048
               + (j * 16 + fr) * 32 + k2;
    Wh[dst] = hi;
    Wl[dst] = lo;
}

// ---------------- prep: W2 -> f16 hi/lo [32 padded][H] ----------------------
__launch_bounds__(256)
__global__ void prep_w2(const float* __restrict__ W2, f16* __restrict__ Wh,
                        f16* __restrict__ Wl) {
    int idx = blockIdx.x * 256 + threadIdx.x;
    int o = idx >> 10;
    float w = (o < OO) ? W2[idx] : 0.f;
    f16 h = (f16)w;
    f16 l = (f16)(w - (float)h);
    Wh[idx] = h;
    Wl[idx] = l;
}

// ---------------- FUSED layer 1: 128x128 tile, barrier-free K-loop ----------
// grid (8, 64), 256 thr. Per block: 4 t-chunks of 128.
// K-loop: 8 iters fully unrolled, 12 contiguous-1KB wave loads/iter straight
// into fragment regs (2-deep reg dbuf, compile-time indices), NO barriers.
// Then: epilogue->yb, barrier, scan (tid<128, direct global spike store),
// barrier. LDS = yb only (67.6 KB, 2 blocks/CU).
__launch_bounds__(256)
__global__ void gemm1_scan1(const f16* __restrict__ Xf, const f16* __restrict__ Wh,
                            const f16* __restrict__ Wl, f16* __restrict__ S1) {
    __shared__ float yb[128 * 132];  // 67,584 B

    const int tid = threadIdx.x;
    const int wave = tid >> 6, lane = tid & 63;

    // XCD swizzle: the 8 h-tiles of one n share an XCD
    const int f = blockIdx.y * 8 + blockIdx.x;
    const int x = f & 7, g = f >> 3;
    const int n = x * 8 + (g & 7);
    const int ht = g >> 3;
    const int h0g = ht * 128;

    const int wm = wave & 1, wn = wave >> 1;
    const int fr = lane & 15, kq = lane >> 4;
    const int lo = fr * 32 + kq * 8;   // lane offset inside a 2048-elem tile

    const f16* bH = Wh + ((size_t)(ht * 2 + wn) * 8) * 2048 + lo;
    const f16* bL = Wl + ((size_t)(ht * 2 + wn) * 8) * 2048 + lo;
    const f16* aN = Xf + (size_t)n * 131072 + (size_t)wm * 16384 + lo;

    float p1 = 0.f, a1 = 0.f, p2 = 0.f, a2 = 0.f;  // scan state (tid<128)

    for (int c = 0; c < 4; ++c) {
        const int t0 = c * 128;
        const int TCe = (TT - t0 < 128) ? (TT - t0) : 128;
        const f16* aC = aN + (size_t)c * 32768;

        f32x4 acc[4][4] = {};
        f16x8 av[2][4], bhv[2][4], blv[2][4];
#pragma unroll
        for (int i = 0; i < 4; ++i) {
            av[0][i]  = *(const f16x8*)(aC + i * 512);
            bhv[0][i] = *(const f16x8*)(bH + i * 512);
            blv[0][i] = *(const f16x8*)(bL + i * 512);
        }
#pragma unroll
        for (int kk = 0; kk < 8; ++kk) {
            const int cur = kk & 1, nxt = cur ^ 1;
            if (kk < 7) {
                const int ko = (kk + 1) * 2048;
#pragma unroll
                for (int i = 0; i < 4; ++i) {
                    av[nxt][i]  = *(const f16x8*)(aC + ko + i * 512);
                    bhv[nxt][i] = *(const f16x8*)(bH + ko + i * 512);
                    blv[nxt][i] = *(const f16x8*)(bL + ko + i * 512);
                }
            }
#pragma unroll
            for (int i = 0; i < 4; ++i)
#pragma unroll
                for (int j = 0; j < 4; ++j) {
                    acc[i][j] = __builtin_amdgcn_mfma_f32_16x16x32_f16(av[cur][i], bhv[cur][j], acc[i][j], 0, 0, 0);
                    acc[i][j] = __builtin_amdgcn_mfma_f32_16x16x32_f16(av[cur][i], blv[cur][j], acc[i][j], 0, 0, 0);
                }
        }

        // epilogue: acc -> yb (t-major, stride 132). Previous chunk's scan
        // finished reading yb at the loop-end barrier.
#pragma unroll
        for (int i = 0; i < 4; ++i)
#pragma unroll
            for (int j = 0; j < 4; ++j) {
                int tr = wm * 64 + i * 16 + kq * 4;
                int hc = wn * 64 + j * 16 + fr;
#pragma unroll
                for (int r = 0; r < 4; ++r)
                    yb[(tr + r) * 132 + hc] = acc[i][j][r];
            }
        __syncthreads();

        // sequential scan; 8-deep LDS prefetch ring; spikes -> global directly
        if (tid < 128) {
            f16* sq = S1 + ((size_t)n * TT + t0) * HH + h0g + tid;
            float rb_[8];
#pragma unroll
            for (int j = 0; j < 8; ++j) rb_[j] = yb[j * 132 + tid];
            int t = 0;
            for (; t + 8 <= TCe; t += 8) {
#pragma unroll
                for (int j = 0; j < 8; ++j) {
                    float xv = rb_[j];
                    int tn = t + j + 8;
                    rb_[j] = (tn < TCe) ? yb[tn * 132 + tid] : 0.f;
                    a1 = D_SR * (a1 + p1);
                    p1 = D_SR * p1 + xv;
                    float ut = C_SR * a1;
                    a2 = D_RF * (a2 + p2);
                    float u = ut + C_RF * a2;
                    float s = (u >= THETA) ? 1.0f : 0.0f;
                    p2 = D_RF * p2 + REFS * s;
                    sq[(size_t)(t + j) * HH] = (f16)s;
                }
            }
            int rem = TCe - t;
#pragma unroll
            for (int j = 0; j < 8; ++j) {
                if (j < rem) {
                    float xv = rb_[j];
                    a1 = D_SR * (a1 + p1);
                    p1 = D_SR * p1 + xv;
                    float ut = C_SR * a1;
                    a2 = D_RF * (a2 + p2);
                    float u = ut + C_RF * a2;
                    float s = (u >= THETA) ? 1.0f : 0.0f;
                    p2 = D_RF * p2 + REFS * s;
                    sq[(size_t)(t + j) * HH] = (f16)s;
                }
            }
        }
        __syncthreads();  // yb reads done; next chunk's epilogue may overwrite
    }
}

// ---------------- GEMM2 (MFMA, split-f16, dbuf K-loop) ----------------------
// grid 250; 256 thr; tile 128 m x 32 o; K=1024, BK=32.
__launch_bounds__(256)
__global__ void gemm2_mfma(const f16* __restrict__ S1, const f16* __restrict__ W2h,
                           const f16* __restrict__ W2l, float* __restrict__ Y2) {
    __shared__ __align__(16) f16 As[2][128 * 32];
    __shared__ __align__(16) f16 Bh[2][32 * 32];
    __shared__ __align__(16) f16 Bl[2][32 * 32];

    const int tid = threadIdx.x;
    const int wave = tid >> 6, lane = tid & 63;
    const int m0 = blockIdx.x * 128;
    const int fr = lane & 15, kq = lane >> 4;

    const f16* gA0 = S1 + (size_t)(m0 + wave * 32 + (lane >> 2)) * HH + (lane & 3) * 8;
    const f16* gA1 = gA0 + (size_t)16 * HH;
    const f16* gB = (wave < 2 ? W2h : W2l) + (size_t)((wave & 1) * 16 + (lane >> 2)) * HH + (lane & 3) * 8;

    auto stage = [&](int kk2, int b) {
        const int ko = kk2 * 32;
        gl2lds16(gA0 + ko, &As[b][wave * 1024]);
        gl2lds16(gA1 + ko, &As[b][wave * 1024 + 512]);
        gl2lds16(gB + ko, (wave < 2 ? &Bh[b][0] : &Bl[b][0]) + (wave & 1) * 512);
    };

    stage(0, 0);

    f32x4 acc[2][2] = {};
    for (int kk = 0; kk < HH / 32; ++kk) {
        __syncthreads();
        if (kk < HH / 32 - 1) stage(kk + 1, (kk + 1) & 1);
        const int b = kk & 1;

        f16x8 a[2], bh[2], bl[2];
#pragma unroll
        for (int i = 0; i < 2; ++i) {
            a[i]  = *(const f16x8*)(&As[b][(wave * 32 + i * 16 + fr) * 32 + kq * 8]);
            bh[i] = *(const f16x8*)(&Bh[b][(i * 16 + fr) * 32 + kq * 8]);
            bl[i] = *(const f16x8*)(&Bl[b][(i * 16 + fr) * 32 + kq * 8]);
        }
#pragma unroll
        for (int i = 0; i < 2; ++i)
#pragma unroll
            for (int j = 0; j < 2; ++j) {
                acc[i][j] = __builtin_amdgcn_mfma_f32_16x16x32_f16(a[i], bh[j], acc[i][j], 0, 0, 0);
                acc[i][j] = __builtin_amdgcn_mfma_f32_16x16x32_f16(a[i], bl[j], acc[i][j], 0, 0, 0);
            }
    }

#pragma unroll
    for (int i = 0; i < 2; ++i)
#pragma unroll
        for (int j = 0; j < 2; ++j) {
            int rbase = m0 + wave * 32 + i * 16 + kq * 4;
            int cc = j * 16 + fr;
            float* p = Y2 + (size_t)rbase * 32 + cc;
#pragma unroll
            for (int r = 0; r < 4; ++r)
                p[(size_t)r * 32] = acc[i][j][r];
        }
}

// ---------------- scan2: LDS-staged, static-index ring ----------------------
__launch_bounds__(256)
__global__ void scan2_k(const float* __restrict__ Y2, float* __restrict__ Out) {
    __shared__ float yc[250 * 32];   // 32,000 B
    __shared__ float sb[OO * TT];    // 36,000 B
    const int n = blockIdx.x, tid = threadIdx.x;

    float p1 = 0.f, a1 = 0.f, p2 = 0.f, a2 = 0.f;  // scan state (tid<32)

    for (int half = 0; half < 2; ++half) {
        const float4* src = (const float4*)(Y2 + ((size_t)n * TT + half * 250) * 32);
        float4* dst = (float4*)yc;
        for (int i = tid; i < 2000; i += 256) dst[i] = src[i];
        __syncthreads();

        if (tid < 32) {
            float rb_[8];
#pragma unroll
            for (int j = 0; j < 8; ++j) rb_[j] = yc[j * 32 + tid];
            int t = 0;
            for (; t + 8 <= 250; t += 8) {
#pragma unroll
                for (int j = 0; j < 8; ++j) {
                    float xv = rb_[j];
                    int tn = t + j + 8;
                    rb_[j] = (tn < 250) ? yc[tn * 32 + tid] : 0.f;
                    a1 = D_SR * (a1 + p1);
                    p1 = D_SR * p1 + xv;
                    float ut = C_SR * a1;
                    a2 = D_RF * (a2 + p2);
                    float u = ut + C_RF * a2;
                    float s = (u >= THETA) ? 1.0f : 0.0f;
                    p2 = D_RF * p2 + REFS * s;
                    if (tid < OO) sb[tid * TT + half * 250 + t + j] = s;
                }
            }
#pragma unroll
            for (int j = 0; j < 8; ++j) {
                if (t + j < 250) {
                    float xv = rb_[j];
                    a1 = D_SR * (a1 + p1);
                    p1 = D_SR * p1 + xv;
                    float ut = C_SR * a1;
                    a2 = D_RF * (a2 + p2);
                    float u = ut + C_RF * a2;
                    float s = (u >= THETA) ? 1.0f : 0.0f;
                    p2 = D_RF * p2 + REFS * s;
                    if (tid < OO) sb[tid * TT + half * 250 + t + j] = s;
                }
            }
        }
        __syncthreads();
    }

    float* on = Out + (size_t)n * OO * TT;
    for (int e = tid; e < OO * TT; e += 256) on[e] = sb[e];
}

extern "C" void kernel_launch(void* const* d_in, const int* in_sizes, int n_in,
                              void* d_out, int out_size, void* d_ws, size_t ws_size,
                              hipStream_t stream) {
    const float* X  = (const float*)d_in[0];
    const float* W1 = (const float*)d_in[1];
    const float* W2 = (const float*)d_in[2];
    float* out = (float*)d_out;

    const size_t s_s1 = (size_t)NN * TT * HH * 2;   // 65,536,000
    const size_t s_Xf = (size_t)NN * 131072 * 2;    // 16,777,216 (t padded 512)
    const size_t s_W  = (size_t)HH * II * 2;        //    524,288 (x2)
    const size_t s_W2 = (size_t)32 * HH * 2;        //     65,536 (x2)
    // + y2 4,096,000 => ~87.5 MB total

    char* w = (char*)d_ws;
    f16*   s1b = (f16*)w;  w += s_s1;
    f16*   Xf  = (f16*)w;  w += s_Xf;
    f16*   W1h = (f16*)w;  w += s_W;
    f16*   W1l = (f16*)w;  w += s_W;
    f16*   W2h = (f16*)w;  w += s_W2;
    f16*   W2l = (f16*)w;  w += s_W2;
    float* y2  = (float*)w;

    prep_x<<<dim3(8, 4, NN), 256, 0, stream>>>(X, Xf);
    prep_w1<<<(HH * II) / 256, 256, 0, stream>>>(W1, W1h, W1l);
    prep_w2<<<(32 * HH) / 256, 256, 0, stream>>>(W2, W2h, W2l);

    gemm1_scan1<<<dim3(8, NN), 256, 0, stream>>>(Xf, W1h, W1l, s1b);

    gemm2_mfma<<<(NN * TT) / 128, 256, 0, stream>>>(s1b, W2h, W2l, y2);
    scan2_k<<<NN, 256, 0, stream>>>(y2, out);
}

// Round 14
// 196.611 us; speedup vs baseline: 1.4119x; 1.4119x over previous
//
#include <hip/hip_runtime.h>

// SNN forward: [GEMM1+scan1 fused, 128x128, LDS-dbuf K-loop (R10 best)] ->
// GEMM2 (64-row tiles, 500 blocks, dbuf) -> scan2 (single-phase LDS, static ring).
// f16 split-2: W = hi + lo (both f16), residual ~2^-24 => fp32-grade MFMA.
// Lessons: ring/dbuf arrays need compile-time indices (R9); register-dbuf
// direct-global K-loops blow VGPR budget (R11/R12, 200 VGPR = 2x slower);
// LDS-staged dbuf with 1 barrier/iter is the robust g1s1 optimum (R10).

#define NN 64
#define II 256
#define HH 1024
#define OO 18
#define TT 500

#define D_SR 0.9048374180359595f   // exp(-1/10)
#define C_SR 0.27182818284590454f  // e/10
#define D_RF 0.36787944117144233f  // exp(-1)
#define C_RF 2.718281828459045f    // e
#define THETA 10.0f
#define REFS (-20.0f)

typedef _Float16 f16;
typedef _Float16 f16x2 __attribute__((ext_vector_type(2)));
typedef _Float16 f16x8 __attribute__((ext_vector_type(8)));
typedef float f32x4 __attribute__((ext_vector_type(4)));

__device__ __forceinline__ void gl2lds16(const void* g, void* l) {
    __builtin_amdgcn_global_load_lds(
        (const __attribute__((address_space(1))) void*)g,
        (__attribute__((address_space(3))) void*)l, 16, 0, 0);
}

// ---------------- prep: X [N][I][T] f32 -> Xb [N*T][I] f16 (transpose) -----
__launch_bounds__(256)
__global__ void prep_x(const float* __restrict__ X, f16* __restrict__ Xb) {
    __shared__ float tile[64][65];
    const int n = blockIdx.z, i0 = blockIdx.y * 64, t0 = blockIdx.x * 64;
    const int tx = threadIdx.x & 63, q = threadIdx.x >> 6;
    const float* Xn = X + (size_t)n * II * TT;
#pragma unroll 4
    for (int j = 0; j < 16; ++j) {
        int il = j * 4 + q;
        int t = t0 + tx;
        tile[il][tx] = (t < TT) ? Xn[(size_t)(i0 + il) * TT + t] : 0.f;
    }
    __syncthreads();
#pragma unroll 4
    for (int j = 0; j < 16; ++j) {
        int tl = j * 4 + q;
        int t = t0 + tl;
        if (t < TT)
            Xb[((size_t)n * TT + t) * II + i0 + tx] = (f16)tile[tx][tl];
    }
}

// ---------------- prep: W1 -> f16 hi/lo [H][I] ------------------------------
__launch_bounds__(256)
__global__ void prep_w1(const float* __restrict__ W1, f16* __restrict__ Wh,
                        f16* __restrict__ Wl) {
    int idx = blockIdx.x * 256 + threadIdx.x;
    float w = W1[idx];
    f16 h = (f16)w;
    f16 l = (f16)(w - (float)h);
    Wh[idx] = h;
    Wl[idx] = l;
}

// ---------------- prep: W2 -> f16 hi/lo [32 padded][H] ----------------------
__launch_bounds__(256)
__global__ void prep_w2(const float* __restrict__ W2, f16* __restrict__ Wh,
                        f16* __restrict__ Wl) {
    int idx = blockIdx.x * 256 + threadIdx.x;
    int o = idx >> 10;
    float w = (o < OO) ? W2[idx] : 0.f;
    f16 h = (f16)w;
    f16 l = (f16)(w - (float)h);
    Wh[idx] = h;
    Wl[idx] = l;
}

// ---------------- FUSED layer 1: 128x128 tile, dbuf K-loop (R10 best) -------
__launch_bounds__(256)
__global__ void gemm1_scan1(const f16* __restrict__ Xb, const f16* __restrict__ Wh,
                            const f16* __restrict__ Wl, f16* __restrict__ S1) {
    __shared__ __align__(16) char smem[128 * 132 * 4];  // 67,584 B
    float* yb = (float*)smem;

    const int tid = threadIdx.x;
    const int wave = tid >> 6, lane = tid & 63;

    // XCD swizzle: the 8 h-tiles of one n share an XCD
    const int f = blockIdx.y * 8 + blockIdx.x;
    const int x = f & 7, g = f >> 3;
    const int n = x * 8 + (g & 7);
    const int ht = g >> 3;
    const int h0g = ht * 128;

    const int rbl = wave * 32 + (lane >> 2);
    const int koff = (lane & 3) * 8;
    const f16* gBh0 = Wh + (size_t)(h0g + rbl) * II + koff;
    const f16* gBl0 = Wl + (size_t)(h0g + rbl) * II + koff;

    const int wm = wave & 1, wn = wave >> 1;
    const int fr = lane & 15, kq = lane >> 4;

    float p1 = 0.f, a1 = 0.f, p2 = 0.f, a2 = 0.f;  // scan state (tid<128)

    for (int c = 0; c < 4; ++c) {
        const int t0 = c * 128;
        const int TCe = (TT - t0 < 128) ? (TT - t0) : 128;

        int r0 = rbl;      if (r0 > TCe - 1) r0 = TCe - 1;
        int r1 = rbl + 16; if (r1 > TCe - 1) r1 = TCe - 1;
        const f16* gA0 = Xb + ((size_t)n * TT + t0 + r0) * II + koff;
        const f16* gA1 = Xb + ((size_t)n * TT + t0 + r1) * II + koff;

        auto stage = [&](int kk2, int b) {
            f16* As_b = (f16*)(smem + b * 24576);
            f16* Bh_b = As_b + 4096;
            f16* Bl_b = As_b + 8192;
            const int ko = kk2 * 32;
            gl2lds16(gA0 + ko, As_b + wave * 1024);
            gl2lds16(gA1 + ko, As_b + wave * 1024 + 512);
            gl2lds16(gBh0 + ko, Bh_b + wave * 1024);
            gl2lds16(gBh0 + 16 * II + ko, Bh_b + wave * 1024 + 512);
            gl2lds16(gBl0 + ko, Bl_b + wave * 1024);
            gl2lds16(gBl0 + 16 * II + ko, Bl_b + wave * 1024 + 512);
        };

        stage(0, 0);  // previous chunk's post-scan barrier protects yb base

        f32x4 acc[4][4] = {};
        for (int kk = 0; kk < 8; ++kk) {
            __syncthreads();                 // buf[kk&1] DMA drained here
            if (kk < 7) stage(kk + 1, (kk + 1) & 1);

            const f16* As_b = (const f16*)(smem + (kk & 1) * 24576);
            const f16* Bh_b = As_b + 4096;
            const f16* Bl_b = As_b + 8192;

            f16x8 av[4], bhv[4], blv[4];
#pragma unroll
            for (int i = 0; i < 4; ++i) {
                av[i]  = *(const f16x8*)(As_b + (wm * 64 + i * 16 + fr) * 32 + kq * 8);
                bhv[i] = *(const f16x8*)(Bh_b + (wn * 64 + i * 16 + fr) * 32 + kq * 8);
                blv[i] = *(const f16x8*)(Bl_b + (wn * 64 + i * 16 + fr) * 32 + kq * 8);
            }
#pragma unroll
            for (int i = 0; i < 4; ++i)
#pragma unroll
                for (int j = 0; j < 4; ++j) {
                    acc[i][j] = __builtin_amdgcn_mfma_f32_16x16x32_f16(av[i], bhv[j], acc[i][j], 0, 0, 0);
                    acc[i][j] = __builtin_amdgcn_mfma_f32_16x16x32_f16(av[i], blv[j], acc[i][j], 0, 0, 0);
                }
        }
        __syncthreads();  // all frag reads done before epilogue overwrites staging

        // epilogue: acc -> yb (t-major, stride 132)
#pragma unroll
        for (int i = 0; i < 4; ++i)
#pragma unroll
            for (int j = 0; j < 4; ++j) {
                int tr = wm * 64 + i * 16 + kq * 4;
                int hc = wn * 64 + j * 16 + fr;
#pragma unroll
                for (int r = 0; r < 4; ++r)
                    yb[(tr + r) * 132 + hc] = acc[i][j][r];
            }
        __syncthreads();

        // sequential scan; 8-deep LDS prefetch ring; spikes -> global directly
        if (tid < 128) {
            f16* sq = S1 + ((size_t)n * TT + t0) * HH + h0g + tid;
            float rb_[8];
#pragma unroll
            for (int j = 0; j < 8; ++j) rb_[j] = yb[j * 132 + tid];
            int t = 0;
            for (; t + 8 <= TCe; t += 8) {
#pragma unroll
                for (int j = 0; j < 8; ++j) {
                    float xv = rb_[j];
                    int tn = t + j + 8;
                    rb_[j] = (tn < TCe) ? yb[tn * 132 + tid] : 0.f;
                    a1 = D_SR * (a1 + p1);
                    p1 = D_SR * p1 + xv;
                    float ut = C_SR * a1;
                    a2 = D_RF * (a2 + p2);
                    float u = ut + C_RF * a2;
                    float s = (u >= THETA) ? 1.0f : 0.0f;
                    p2 = D_RF * p2 + REFS * s;
                    sq[(size_t)(t + j) * HH] = (f16)s;
                }
            }
            int rem = TCe - t;
#pragma unroll
            for (int j = 0; j < 8; ++j) {
                if (j < rem) {
                    float xv = rb_[j];
                    a1 = D_SR * (a1 + p1);
                    p1 = D_SR * p1 + xv;
                    float ut = C_SR * a1;
                    a2 = D_RF * (a2 + p2);
                    float u = ut + C_RF * a2;
                    float s = (u >= THETA) ? 1.0f : 0.0f;
                    p2 = D_RF * p2 + REFS * s;
                    sq[(size_t)(t + j) * HH] = (f16)s;
                }
            }
        }
        __syncthreads();  // yb reads done; next chunk's epilogue may overwrite
    }
}

// ---------------- GEMM2 (MFMA, split-f16, dbuf, 64-row tiles) ---------------
// grid 500 (2 blocks/CU); 256 thr; tile 64 m x 32 o; K=1024, BK=32.
// Small tiles: full CU coverage + co-resident block hides the streaming-A
// load latency that a 250-block 1/CU launch exposes.
__launch_bounds__(256)
__global__ void gemm2_mfma(const f16* __restrict__ S1, const f16* __restrict__ W2h,
                           const f16* __restrict__ W2l, float* __restrict__ Y2) {
    __shared__ __align__(16) f16 As[2][64 * 32];  // 2 x 4 KB
    __shared__ __align__(16) f16 Bh[2][32 * 32];  // 2 x 2 KB
    __shared__ __align__(16) f16 Bl[2][32 * 32];  // 2 x 2 KB

    const int tid = threadIdx.x;
    const int wave = tid >> 6, lane = tid & 63;
    const int m0 = blockIdx.x * 64;
    const int fr = lane & 15, kq = lane >> 4;

    const f16* gA = S1 + (size_t)(m0 + wave * 16 + (lane >> 2)) * HH + (lane & 3) * 8;
    const f16* gB = (wave < 2 ? W2h : W2l) + (size_t)((wave & 1) * 16 + (lane >> 2)) * HH + (lane & 3) * 8;

    auto stage = [&](int kk2, int b) {
        const int ko = kk2 * 32;
        gl2lds16(gA + ko, &As[b][wave * 512]);
        gl2lds16(gB + ko, (wave < 2 ? &Bh[b][0] : &Bl[b][0]) + (wave & 1) * 512);
    };

    stage(0, 0);

    f32x4 acc[2] = {};
    for (int kk = 0; kk < HH / 32; ++kk) {
        __syncthreads();
        if (kk < HH / 32 - 1) stage(kk + 1, (kk + 1) & 1);
        const int b = kk & 1;

        f16x8 a, bh[2], bl[2];
        a = *(const f16x8*)(&As[b][(wave * 16 + fr) * 32 + kq * 8]);
#pragma unroll
        for (int j = 0; j < 2; ++j) {
            bh[j] = *(const f16x8*)(&Bh[b][(j * 16 + fr) * 32 + kq * 8]);
            bl[j] = *(const f16x8*)(&Bl[b][(j * 16 + fr) * 32 + kq * 8]);
        }
#pragma unroll
        for (int j = 0; j < 2; ++j) {
            acc[j] = __builtin_amdgcn_mfma_f32_16x16x32_f16(a, bh[j], acc[j], 0, 0, 0);
            acc[j] = __builtin_amdgcn_mfma_f32_16x16x32_f16(a, bl[j], acc[j], 0, 0, 0);
        }
    }

#pragma unroll
    for (int j = 0; j < 2; ++j) {
        int rbase = m0 + wave * 16 + kq * 4;
        int cc = j * 16 + fr;
        float* p = Y2 + (size_t)rbase * 32 + cc;
#pragma unroll
        for (int r = 0; r < 4; ++r)
            p[(size_t)r * 32] = acc[j][r];
    }
}

// ---------------- scan2: single-phase LDS, static-index ring ----------------
// grid 64 (n), 256 thr. Whole 500x32 y2 slice (62.5 KB) staged at once:
// one load phase, one barrier, 500 uninterrupted ring steps, writeout.
__launch_bounds__(256)
__global__ void scan2_k(const float* __restrict__ Y2, float* __restrict__ Out) {
    __shared__ float yc[TT * 32];    // 64,000 B
    __shared__ float sb[OO * TT];    // 36,000 B
    const int n = blockIdx.x, tid = threadIdx.x;

    const float4* src = (const float4*)(Y2 + (size_t)n * TT * 32);
    float4* dst = (float4*)yc;
    for (int i = tid; i < TT * 8; i += 256) dst[i] = src[i];
    __syncthreads();

    if (tid < 32) {
        float p1 = 0.f, a1 = 0.f, p2 = 0.f, a2 = 0.f;
        float rb_[8];
#pragma unroll
        for (int j = 0; j < 8; ++j) rb_[j] = yc[j * 32 + tid];
        int t = 0;
        for (; t + 8 <= TT; t += 8) {
#pragma unroll
            for (int j = 0; j < 8; ++j) {
                float xv = rb_[j];
                int tn = t + j + 8;
                rb_[j] = (tn < TT) ? yc[tn * 32 + tid] : 0.f;
                a1 = D_SR * (a1 + p1);
                p1 = D_SR * p1 + xv;
                float ut = C_SR * a1;
                a2 = D_RF * (a2 + p2);
                float u = ut + C_RF * a2;
                float s = (u >= THETA) ? 1.0f : 0.0f;
                p2 = D_RF * p2 + REFS * s;
                if (tid < OO) sb[tid * TT + t + j] = s;
            }
        }
#pragma unroll
        for (int j = 0; j < 8; ++j) {
            if (t + j < TT) {
                float xv = rb_[j];
                a1 = D_SR * (a1 + p1);
                p1 = D_SR * p1 + xv;
                float ut = C_SR * a1;
                a2 = D_RF * (a2 + p2);
                float u = ut + C_RF * a2;
                float s = (u >= THETA) ? 1.0f : 0.0f;
                p2 = D_RF * p2 + REFS * s;
                if (tid < OO) sb[tid * TT + t + j] = s;
            }
        }
    }
    __syncthreads();

    float* on = Out + (size_t)n * OO * TT;
    for (int e = tid; e < OO * TT; e += 256) on[e] = sb[e];
}

extern "C" void kernel_launch(void* const* d_in, const int* in_sizes, int n_in,
                              void* d_out, int out_size, void* d_ws, size_t ws_size,
                              hipStream_t stream) {
    const float* X  = (const float*)d_in[0];
    const float* W1 = (const float*)d_in[1];
    const float* W2 = (const float*)d_in[2];
    float* out = (float*)d_out;

    const size_t s_s1 = (size_t)NN * TT * HH * 2;   // 65,536,000
    const size_t s_Xb = (size_t)NN * TT * II * 2;   // 16,384,000
    const size_t s_W  = (size_t)HH * II * 2;        //    524,288 (x2)
    const size_t s_W2 = (size_t)32 * HH * 2;        //     65,536 (x2)
    // + y2 4,096,000 => ~87 MB total

    char* w = (char*)d_ws;
    f16*   s1b = (f16*)w;  w += s_s1;
    f16*   Xb  = (f16*)w;  w += s_Xb;
    f16*   W1h = (f16*)w;  w += s_W;
    f16*   W1l = (f16*)w;  w += s_W;
    f16*   W2h = (f16*)w;  w += s_W2;
    f16*   W2l = (f16*)w;  w += s_W2;
    float* y2  = (float*)w;

    prep_x<<<dim3(8, 4, NN), 256, 0, stream>>>(X, Xb);
    prep_w1<<<(HH * II) / 256, 256, 0, stream>>>(W1, W1h, W1l);
    prep_w2<<<(32 * HH) / 256, 256, 0, stream>>>(W2, W2h, W2l);

    gemm1_scan1<<<dim3(8, NN), 256, 0, stream>>>(Xb, W1h, W1l, s1b);

    gemm2_mfma<<<(NN * TT) / 64, 256, 0, stream>>>(s1b, W2h, W2l, y2);
    scan2_k<<<NN, 256, 0, stream>>>(y2, out);
}